// Round 7
// baseline (353.181 us; speedup 1.0000x reference)
//
#include <hip/hip_runtime.h>
#include <hip/hip_bf16.h>

#define BATCH 8
#define NNODE 2048
#define FDIM 256
#define HD 256
#define NH 4
#define MROWS (BATCH*NNODE)

typedef float f32x4 __attribute__((ext_vector_type(4)));
typedef short s16x8 __attribute__((ext_vector_type(8)));
typedef unsigned short ushort_t;

#define MFMA __builtin_amdgcn_mfma_f32_16x16x32_bf16
#define SCHED0() __builtin_amdgcn_sched_barrier(0)
#define SBAR() __builtin_amdgcn_s_barrier()

// truncation hi/lo split: f = hi + lo + eps, |eps| <= 2^-16 |f|
__device__ __forceinline__ void split2(float f, ushort_t& h, ushort_t& l) {
    unsigned u = __builtin_bit_cast(unsigned, f);
    h = (ushort_t)(u >> 16);
    float fh = __builtin_bit_cast(float, u & 0xffff0000u);
    float lo = f - fh;                       // exact
    l = (ushort_t)(__builtin_bit_cast(unsigned, lo) >> 16);
}

// global -> LDS direct (wave-uniform LDS base + lane*16; per-lane global src)
#define GLOAD16(gp, lp) __builtin_amdgcn_global_load_lds( \
    (const __attribute__((address_space(1))) void*)(gp),  \
    (__attribute__((address_space(3))) void*)(lp), 16, 0, 0)

// ---------------------------------------------------------------------------
// wprep: wt_hi/lo[n][k] = trunc-split(W[k][n])
// ---------------------------------------------------------------------------
__global__ __launch_bounds__(256) void wprep_kernel(
    const float* __restrict__ Wm,
    ushort_t* __restrict__ wt_hi, ushort_t* __restrict__ wt_lo)
{
    const int nn = blockIdx.x, k = threadIdx.x;
    ushort_t h, l;
    split2(Wm[(size_t)k * HD + nn], h, l);
    wt_hi[nn * FDIM + k] = h;
    wt_lo[nn * FDIM + k] = l;
}

// ---------------------------------------------------------------------------
// GEMM1: Wh = features @ W. 64x64 tiles, BK=64, K=256 (4 tiles).
// grid (256, 4); 4 waves 2x2; wave tile 32x32. Emits WhT hi/lo + e.
// (unchanged from R6 — passing; will surface in counters if dominant)
// ---------------------------------------------------------------------------
__global__ __launch_bounds__(256, 4) void gemm1_kernel(
    const float* __restrict__ features,
    const ushort_t* __restrict__ wt_hi,
    const ushort_t* __restrict__ wt_lo,
    ushort_t* __restrict__ WhT_hi,
    ushort_t* __restrict__ WhT_lo,
    float* __restrict__ e_out)
{
    __shared__ __align__(16) ushort_t Ah[64 * 64];
    __shared__ __align__(16) ushort_t Al[64 * 64];
    __shared__ __align__(16) ushort_t Bh[64 * 64];
    __shared__ __align__(16) ushort_t Bl[64 * 64];
    __shared__ float red[64][2];

    const int tid = threadIdx.x, lane = tid & 63, w = tid >> 6;
    const int wr = w >> 1, wc = w & 1;
    const int row0 = blockIdx.x * 64;
    const int head = blockIdx.y;
    const int col0 = head * 64;

    const float* Ab = features + (size_t)row0 * FDIM;
    const ushort_t* Bhg = wt_hi + (size_t)col0 * FDIM;
    const ushort_t* Blg = wt_lo + (size_t)col0 * FDIM;

    const int sr0 = tid >> 3;
    const int sg8 = tid & 7;
    const int bc = (lane >> 3);
    const int bs = lane & 7;

    f32x4 ar[4];
    f32x4 acc[2][2];
    #pragma unroll
    for (int m = 0; m < 2; ++m)
        #pragma unroll
        for (int n = 0; n < 2; ++n) acc[m][n] = (f32x4)0.f;

    #define G1_LOADA(K0) do {                                                  \
        _Pragma("unroll")                                                      \
        for (int i = 0; i < 2; ++i) {                                          \
            const int r = sr0 + 32 * i;                                        \
            ar[2*i]   = *(const f32x4*)&Ab[(size_t)r * FDIM + (K0) + sg8 * 8]; \
            ar[2*i+1] = *(const f32x4*)&Ab[(size_t)r * FDIM + (K0) + sg8 * 8 + 4]; \
        }                                                                      \
    } while (0)

    #define G1_STAGEA() do {                                                   \
        _Pragma("unroll")                                                      \
        for (int i = 0; i < 2; ++i) {                                          \
            const int r = sr0 + 32 * i;                                        \
            s16x8 vh, vl; ushort_t hh, ll;                                     \
            _Pragma("unroll")                                                  \
            for (int j = 0; j < 4; ++j) {                                      \
                split2(ar[2*i][j], hh, ll);  vh[j] = (short)hh; vl[j] = (short)ll; \
            }                                                                  \
            _Pragma("unroll")                                                  \
            for (int j = 0; j < 4; ++j) {                                      \
                split2(ar[2*i+1][j], hh, ll); vh[4+j] = (short)hh; vl[4+j] = (short)ll; \
            }                                                                  \
            const int off = r * 64 + ((sg8 ^ (r & 7)) << 3);                   \
            *(s16x8*)&Ah[off] = vh; *(s16x8*)&Al[off] = vl;                    \
        }                                                                      \
    } while (0)

    #define G1_STAGEB(K0) do {                                                 \
        _Pragma("unroll")                                                      \
        for (int qq = 0; qq < 2; ++qq) {                                       \
            const int q = w + qq * 4;                                          \
            const int c = q * 8 + bc;                                          \
            const int g = bs ^ (c & 7);                                        \
            GLOAD16(&Bhg[(size_t)c * FDIM + (K0) + g * 8], &Bh[q * 512]);      \
            GLOAD16(&Blg[(size_t)c * FDIM + (K0) + g * 8], &Bl[q * 512]);      \
        }                                                                      \
    } while (0)

    G1_LOADA(0);
    for (int t = 0; t < 4; ++t) {
        G1_STAGEB(t * 64);
        G1_STAGEA();
        if (t < 3) G1_LOADA((t + 1) * 64);
        if (t < 3) { asm volatile("s_waitcnt lgkmcnt(0) vmcnt(4)" ::: "memory"); }
        else       { asm volatile("s_waitcnt lgkmcnt(0) vmcnt(0)" ::: "memory"); }
        SCHED0(); SBAR(); SCHED0();
        #pragma unroll
        for (int kh = 0; kh < 2; ++kh) {
            const int kg = kh * 4 + (lane >> 4);
            s16x8 afh[2], afl[2], bfh[2], bfl[2];
            #pragma unroll
            for (int m = 0; m < 2; ++m) {
                const int r = wr * 32 + m * 16 + (lane & 15);
                const int off = r * 64 + ((kg ^ (r & 7)) << 3);
                afh[m] = *(const s16x8*)&Ah[off];
                afl[m] = *(const s16x8*)&Al[off];
            }
            #pragma unroll
            for (int n = 0; n < 2; ++n) {
                const int c = wc * 32 + n * 16 + (lane & 15);
                const int off = c * 64 + ((kg ^ (c & 7)) << 3);
                bfh[n] = *(const s16x8*)&Bh[off];
                bfl[n] = *(const s16x8*)&Bl[off];
            }
            #pragma unroll
            for (int m = 0; m < 2; ++m)
                #pragma unroll
                for (int n = 0; n < 2; ++n) {
                    acc[m][n] = MFMA(afh[m], bfh[n], acc[m][n], 0, 0, 0);
                    acc[m][n] = MFMA(afh[m], bfl[n], acc[m][n], 0, 0, 0);
                    acc[m][n] = MFMA(afl[m], bfh[n], acc[m][n], 0, 0, 0);
                }
        }
        SCHED0(); SBAR(); SCHED0();
    }

    // ---- e: row sums of squares (64 cols of this head)
    #pragma unroll
    for (int m = 0; m < 2; ++m)
        #pragma unroll
        for (int j = 0; j < 4; ++j) {
            float p = acc[m][0][j] * acc[m][0][j] + acc[m][1][j] * acc[m][1][j];
            p += __shfl_xor(p, 1, 64);
            p += __shfl_xor(p, 2, 64);
            p += __shfl_xor(p, 4, 64);
            p += __shfl_xor(p, 8, 64);
            if ((lane & 15) == 0)
                red[wr * 32 + m * 16 + (lane >> 4) * 4 + j][wc] = p;
        }

    // ---- WhT transpose via LDS (reuse Ah/Al)
    __syncthreads();
    ushort_t* Th = Ah;
    ushort_t* Tl = Al;
    #pragma unroll
    for (int m = 0; m < 2; ++m)
        #pragma unroll
        for (int n = 0; n < 2; ++n)
            #pragma unroll
            for (int j = 0; j < 4; ++j) {
                const int rr = wr * 32 + m * 16 + (lane >> 4) * 4 + j;
                const int cc = wc * 32 + n * 16 + (lane & 15);
                const int ad = cc * 64 + ((((rr >> 3) ^ (cc & 7))) << 3) + (rr & 7);
                ushort_t hh, ll;
                split2(acc[m][n][j], hh, ll);
                Th[ad] = hh; Tl[ad] = ll;
            }
    __syncthreads();

    if (tid < 64) {
        const int rg = row0 + tid;
        e_out[((size_t)((rg >> 11) * NH + head)) * NNODE + (rg & 2047)] =
            red[tid][0] + red[tid][1];
    }
    const int bb = row0 >> 11, node0 = row0 & 2047;
    #pragma unroll
    for (int i = 0; i < 2; ++i) {
        const int gid = tid + 256 * i;
        const int c = gid >> 3, gr = gid & 7;
        const int ad = c * 64 + ((gr ^ (c & 7)) << 3);
        uint4 vh = *(const uint4*)&Th[ad];
        uint4 vl = *(const uint4*)&Tl[ad];
        const size_t o = ((size_t)bb * HD + col0 + c) * NNODE + node0 + gr * 8;
        *(uint4*)&WhT_hi[o] = vh;
        *(uint4*)&WhT_lo[o] = vl;
    }
}

// ---------------------------------------------------------------------------
// softmax stats + att
// ---------------------------------------------------------------------------
__global__ __launch_bounds__(256) void sm_kernel(
    const float* __restrict__ e, float* __restrict__ ms)
{
    __shared__ float red[8];
    const int bh = blockIdx.x, tid = threadIdx.x;
    const int lane = tid & 63, w = tid >> 6;
    const float* row = e + (size_t)bh * NNODE;
    float mx = -3.0e38f;
    for (int n = tid; n < NNODE; n += 256) mx = fmaxf(mx, row[n]);
    #pragma unroll
    for (int off = 32; off; off >>= 1) mx = fmaxf(mx, __shfl_xor(mx, off, 64));
    if (lane == 0) red[w] = mx;
    __syncthreads();
    mx = fmaxf(fmaxf(red[0], red[1]), fmaxf(red[2], red[3]));
    float s = 0.f;
    for (int n = tid; n < NNODE; n += 256) s += expf(row[n] - mx);
    #pragma unroll
    for (int off = 32; off; off >>= 1) s += __shfl_xor(s, off, 64);
    if (lane == 0) red[4 + w] = s;
    __syncthreads();
    if (tid == 0) {
        ms[bh * 2] = mx;
        ms[bh * 2 + 1] = red[4] + red[5] + red[6] + red[7];
    }
}

__global__ __launch_bounds__(256) void att_kernel(
    const float* __restrict__ e, const float* __restrict__ ms,
    float* __restrict__ attv)
{
    const int i = blockIdx.x * 256 + threadIdx.x;
    const int b = i >> 11, n = i & 2047;
    float a = 0.f;
    #pragma unroll
    for (int h = 0; h < NH; ++h) {
        const int bh = b * NH + h;
        a += expf(e[(size_t)bh * NNODE + n] - ms[bh * 2]) / ms[bh * 2 + 1];
    }
    attv[i] = 0.25f * a;
}

// ---------------------------------------------------------------------------
// GEMM2: out = relu(att[row]*(adj @ Wh) + bias). 128x64 block tiles, BK=64.
// grid (16,4,8) = 512 blocks, NO LDS, NO BARRIERS: 4 independent waves,
// each 32 rows x 64 cols. A fp32 and B bf16(hi/lo) loaded straight from
// global into MFMA fragment registers (both layouts are 8-contiguous-k
// per lane). A-raw and B-hi double-buffered (1 tile ahead); B-lo loaded
// early in-tile (L2/L3-resident, latency hidden by A-convert).
// ---------------------------------------------------------------------------
__global__ __launch_bounds__(256) void gemm2_kernel(
    const float* __restrict__ adj,
    const ushort_t* __restrict__ WhT_hi,
    const ushort_t* __restrict__ WhT_lo,
    const float* __restrict__ att,
    const float* __restrict__ bias,
    float* __restrict__ out)
{
    const int tid = threadIdx.x, lane = tid & 63, w = tid >> 6;
    const int b = blockIdx.z;
    const int row0 = blockIdx.x * 128, col0 = blockIdx.y * 64;

    // A: row = row0 + w*32 + (lane&15) (+16 for m=1); k = (lane>>4)*8 + ks*32 + t*64
    const float* pA = adj + (size_t)b * NNODE * NNODE
                    + (size_t)(row0 + w * 32 + (lane & 15)) * NNODE
                    + ((lane >> 4) * 8);
    // B: col = col0 + n*16 + (lane&15); k = (lane>>4)*8 + ks*32 + t*64
    const size_t bbase = ((size_t)b * HD + col0 + (lane & 15)) * NNODE + ((lane >> 4) * 8);
    const ushort_t* pBh = WhT_hi + bbase;
    const ushort_t* pBl = WhT_lo + bbase;

    f32x4 a0[8], a1[8];                 // raw A sets [m*4 + ks*2 + half]
    s16x8 bh0[8], bh1[8], bl_[8];       // B frags [n*2 + ks]
    s16x8 afh[2][2], afl[2][2];         // converted A frags [m][ks]
    f32x4 acc[2][4];
    #pragma unroll
    for (int m = 0; m < 2; ++m)
        #pragma unroll
        for (int n = 0; n < 4; ++n) acc[m][n] = (f32x4)0.f;

    #define G2_LOADA(AR, K0) do {                                               \
        _Pragma("unroll")                                                       \
        for (int m = 0; m < 2; ++m)                                             \
        _Pragma("unroll")                                                       \
        for (int ks = 0; ks < 2; ++ks) {                                        \
            AR[m*4 + ks*2 + 0] = *(const f32x4*)&pA[(size_t)m * 16 * NNODE + (K0) + ks * 32]; \
            AR[m*4 + ks*2 + 1] = *(const f32x4*)&pA[(size_t)m * 16 * NNODE + (K0) + ks * 32 + 4]; \
        }                                                                       \
    } while (0)

    #define G2_LOADBH(BH, K0) do {                                              \
        _Pragma("unroll")                                                       \
        for (int n = 0; n < 4; ++n)                                             \
        _Pragma("unroll")                                                       \
        for (int ks = 0; ks < 2; ++ks)                                          \
            BH[n*2 + ks] = *(const s16x8*)&pBh[(size_t)n * 16 * NNODE + (K0) + ks * 32]; \
    } while (0)

    #define G2_LOADBL(BL, K0) do {                                              \
        _Pragma("unroll")                                                       \
        for (int n = 0; n < 4; ++n)                                             \
        _Pragma("unroll")                                                       \
        for (int ks = 0; ks < 2; ++ks)                                          \
            BL[n*2 + ks] = *(const s16x8*)&pBl[(size_t)n * 16 * NNODE + (K0) + ks * 32]; \
    } while (0)

    #define G2_CONVERT(AR) do {                                                 \
        _Pragma("unroll")                                                       \
        for (int m = 0; m < 2; ++m)                                             \
        _Pragma("unroll")                                                       \
        for (int ks = 0; ks < 2; ++ks) {                                        \
            ushort_t hh, ll;                                                    \
            _Pragma("unroll")                                                   \
            for (int h2 = 0; h2 < 2; ++h2)                                      \
            _Pragma("unroll")                                                   \
            for (int j = 0; j < 4; ++j) {                                       \
                split2(AR[m*4 + ks*2 + h2][j], hh, ll);                         \
                afh[m][ks][h2 * 4 + j] = (short)hh;                             \
                afl[m][ks][h2 * 4 + j] = (short)ll;                             \
            }                                                                   \
        }                                                                       \
    } while (0)

    #define G2_MFMA(BH, BL) do {                                                \
        _Pragma("unroll")                                                       \
        for (int ks = 0; ks < 2; ++ks) {                                        \
            __builtin_amdgcn_s_setprio(1);                                      \
            _Pragma("unroll")                                                   \
            for (int m = 0; m < 2; ++m)                                         \
            _Pragma("unroll")                                                   \
            for (int n = 0; n < 4; ++n) {                                       \
                acc[m][n] = MFMA(afh[m][ks], BH[n*2+ks], acc[m][n], 0, 0, 0);   \
                acc[m][n] = MFMA(afh[m][ks], BL[n*2+ks], acc[m][n], 0, 0, 0);   \
                acc[m][n] = MFMA(afl[m][ks], BH[n*2+ks], acc[m][n], 0, 0, 0);   \
            }                                                                   \
            __builtin_amdgcn_s_setprio(0);                                      \
        }                                                                       \
    } while (0)

    // prologue: tile 0's A and B-hi in flight
    G2_LOADBH(bh0, 0);
    G2_LOADA(a0, 0);

    #pragma unroll 1
    for (int t = 0; t < 32; t += 2) {
        // ---- even tile t (cur = a0/bh0, next = a1/bh1)
        G2_LOADBL(bl_, t * 64);
        G2_LOADBH(bh1, (t + 1) * 64);
        G2_LOADA(a1, (t + 1) * 64);
        G2_CONVERT(a0);
        G2_MFMA(bh0, bl_);
        // ---- odd tile t+1 (cur = a1/bh1, next = a0/bh0)
        G2_LOADBL(bl_, (t + 1) * 64);
        if (t + 2 < 32) {
            G2_LOADBH(bh0, (t + 2) * 64);
            G2_LOADA(a0, (t + 2) * 64);
        }
        G2_CONVERT(a1);
        G2_MFMA(bh1, bl_);
    }

    // epilogue
    const float* attb = att + (size_t)b * NNODE;
    #pragma unroll
    for (int n = 0; n < 4; ++n) {
        const int c = col0 + n * 16 + (lane & 15);
        const float bv = bias[c];
        #pragma unroll
        for (int m = 0; m < 2; ++m)
            #pragma unroll
            for (int j = 0; j < 4; ++j) {
                const int row = row0 + w * 32 + m * 16 + (lane >> 4) * 4 + j;
                out[((size_t)b * NNODE + row) * HD + c] =
                    fmaxf(fmaf(acc[m][n][j], attb[row], bv), 0.f);
            }
    }
}

extern "C" void kernel_launch(void* const* d_in, const int* in_sizes, int n_in,
                              void* d_out, int out_size, void* d_ws, size_t ws_size,
                              hipStream_t stream) {
    const float* features = (const float*)d_in[0];
    const float* adj      = (const float*)d_in[1];
    const float* Wm       = (const float*)d_in[2];
    const float* bias     = (const float*)d_in[3];
    float* out = (float*)d_out;

    ushort_t* WhT_hi = (ushort_t*)d_ws;
    ushort_t* WhT_lo = WhT_hi + (size_t)BATCH * HD * NNODE;
    ushort_t* wt_hi  = WhT_lo + (size_t)BATCH * HD * NNODE;
    ushort_t* wt_lo  = wt_hi + FDIM * HD;
    float* e    = (float*)(wt_lo + FDIM * HD);
    float* ms   = e + (size_t)BATCH * NH * NNODE;
    float* attv = ms + 64;

    wprep_kernel<<<HD, 256, 0, stream>>>(Wm, wt_hi, wt_lo);
    gemm1_kernel<<<dim3(MROWS / 64, NH), 256, 0, stream>>>(
        features, wt_hi, wt_lo, WhT_hi, WhT_lo, e);
    sm_kernel<<<BATCH * NH, 256, 0, stream>>>(e, ms);
    att_kernel<<<MROWS / 256, 256, 0, stream>>>(e, ms, attv);
    gemm2_kernel<<<dim3(NNODE / 128, HD / 64, BATCH), 256, 0, stream>>>(
        adj, WhT_hi, WhT_lo, attv, bias, out);
}

// Round 8
// 267.683 us; speedup vs baseline: 1.3194x; 1.3194x over previous
//
#include <hip/hip_runtime.h>
#include <hip/hip_bf16.h>

#define BATCH 8
#define NNODE 2048
#define FDIM 256
#define HD 256
#define NH 4
#define MROWS (BATCH*NNODE)

typedef float f32x4 __attribute__((ext_vector_type(4)));
typedef short s16x8 __attribute__((ext_vector_type(8)));
typedef unsigned short ushort_t;

#define MFMA __builtin_amdgcn_mfma_f32_16x16x32_bf16
#define SCHED0() __builtin_amdgcn_sched_barrier(0)
#define SBAR() __builtin_amdgcn_s_barrier()

// RNE round to bf16
__device__ __forceinline__ ushort_t f2bf(float f) {
    unsigned u = __builtin_bit_cast(unsigned, f);
    u += 0x7fffu + ((u >> 16) & 1u);
    return (ushort_t)(u >> 16);
}
// truncation hi/lo split: f = hi + lo + eps, |eps| <= 2^-16 |f|
__device__ __forceinline__ void split2(float f, ushort_t& h, ushort_t& l) {
    unsigned u = __builtin_bit_cast(unsigned, f);
    h = (ushort_t)(u >> 16);
    float fh = __builtin_bit_cast(float, u & 0xffff0000u);
    float lo = f - fh;                       // exact
    l = (ushort_t)(__builtin_bit_cast(unsigned, lo) >> 16);
}

// global -> LDS direct (wave-uniform LDS base + lane*16; per-lane global src)
#define GLOAD16(gp, lp) __builtin_amdgcn_global_load_lds( \
    (const __attribute__((address_space(1))) void*)(gp),  \
    (__attribute__((address_space(3))) void*)(lp), 16, 0, 0)

// ---------------------------------------------------------------------------
// wprep: wt_hi/lo[n][k] = trunc-split(W[k][n])
// ---------------------------------------------------------------------------
__global__ __launch_bounds__(256) void wprep_kernel(
    const float* __restrict__ Wm,
    ushort_t* __restrict__ wt_hi, ushort_t* __restrict__ wt_lo)
{
    const int nn = blockIdx.x, k = threadIdx.x;
    ushort_t h, l;
    split2(Wm[(size_t)k * HD + nn], h, l);
    wt_hi[nn * FDIM + k] = h;
    wt_lo[nn * FDIM + k] = l;
}

// ---------------------------------------------------------------------------
// GEMM1: Wh = features @ W. 64x64 tiles, BK=64, K=256 (4 tiles).
// grid (256, 4); 4 waves 2x2; wave tile 32x32. Emits WhT hi/lo + e.
// (unchanged from R6 — never appears in top-5; not the bottleneck)
// ---------------------------------------------------------------------------
__global__ __launch_bounds__(256, 4) void gemm1_kernel(
    const float* __restrict__ features,
    const ushort_t* __restrict__ wt_hi,
    const ushort_t* __restrict__ wt_lo,
    ushort_t* __restrict__ WhT_hi,
    ushort_t* __restrict__ WhT_lo,
    float* __restrict__ e_out)
{
    __shared__ __align__(16) ushort_t Ah[64 * 64];
    __shared__ __align__(16) ushort_t Al[64 * 64];
    __shared__ __align__(16) ushort_t Bh[64 * 64];
    __shared__ __align__(16) ushort_t Bl[64 * 64];
    __shared__ float red[64][2];

    const int tid = threadIdx.x, lane = tid & 63, w = tid >> 6;
    const int wr = w >> 1, wc = w & 1;
    const int row0 = blockIdx.x * 64;
    const int head = blockIdx.y;
    const int col0 = head * 64;

    const float* Ab = features + (size_t)row0 * FDIM;
    const ushort_t* Bhg = wt_hi + (size_t)col0 * FDIM;
    const ushort_t* Blg = wt_lo + (size_t)col0 * FDIM;

    const int sr0 = tid >> 3;
    const int sg8 = tid & 7;
    const int bc = (lane >> 3);
    const int bs = lane & 7;

    f32x4 ar[4];
    f32x4 acc[2][2];
    #pragma unroll
    for (int m = 0; m < 2; ++m)
        #pragma unroll
        for (int n = 0; n < 2; ++n) acc[m][n] = (f32x4)0.f;

    #define G1_LOADA(K0) do {                                                  \
        _Pragma("unroll")                                                      \
        for (int i = 0; i < 2; ++i) {                                          \
            const int r = sr0 + 32 * i;                                        \
            ar[2*i]   = *(const f32x4*)&Ab[(size_t)r * FDIM + (K0) + sg8 * 8]; \
            ar[2*i+1] = *(const f32x4*)&Ab[(size_t)r * FDIM + (K0) + sg8 * 8 + 4]; \
        }                                                                      \
    } while (0)

    #define G1_STAGEA() do {                                                   \
        _Pragma("unroll")                                                      \
        for (int i = 0; i < 2; ++i) {                                          \
            const int r = sr0 + 32 * i;                                        \
            s16x8 vh, vl; ushort_t hh, ll;                                     \
            _Pragma("unroll")                                                  \
            for (int j = 0; j < 4; ++j) {                                      \
                split2(ar[2*i][j], hh, ll);  vh[j] = (short)hh; vl[j] = (short)ll; \
            }                                                                  \
            _Pragma("unroll")                                                  \
            for (int j = 0; j < 4; ++j) {                                      \
                split2(ar[2*i+1][j], hh, ll); vh[4+j] = (short)hh; vl[4+j] = (short)ll; \
            }                                                                  \
            const int off = r * 64 + ((sg8 ^ (r & 7)) << 3);                   \
            *(s16x8*)&Ah[off] = vh; *(s16x8*)&Al[off] = vl;                    \
        }                                                                      \
    } while (0)

    #define G1_STAGEB(K0) do {                                                 \
        _Pragma("unroll")                                                      \
        for (int qq = 0; qq < 2; ++qq) {                                       \
            const int q = w + qq * 4;                                          \
            const int c = q * 8 + bc;                                          \
            const int g = bs ^ (c & 7);                                        \
            GLOAD16(&Bhg[(size_t)c * FDIM + (K0) + g * 8], &Bh[q * 512]);      \
            GLOAD16(&Blg[(size_t)c * FDIM + (K0) + g * 8], &Bl[q * 512]);      \
        }                                                                      \
    } while (0)

    G1_LOADA(0);
    for (int t = 0; t < 4; ++t) {
        G1_STAGEB(t * 64);
        G1_STAGEA();
        if (t < 3) G1_LOADA((t + 1) * 64);
        if (t < 3) { asm volatile("s_waitcnt lgkmcnt(0) vmcnt(4)" ::: "memory"); }
        else       { asm volatile("s_waitcnt lgkmcnt(0) vmcnt(0)" ::: "memory"); }
        SCHED0(); SBAR(); SCHED0();
        #pragma unroll
        for (int kh = 0; kh < 2; ++kh) {
            const int kg = kh * 4 + (lane >> 4);
            s16x8 afh[2], afl[2], bfh[2], bfl[2];
            #pragma unroll
            for (int m = 0; m < 2; ++m) {
                const int r = wr * 32 + m * 16 + (lane & 15);
                const int off = r * 64 + ((kg ^ (r & 7)) << 3);
                afh[m] = *(const s16x8*)&Ah[off];
                afl[m] = *(const s16x8*)&Al[off];
            }
            #pragma unroll
            for (int n = 0; n < 2; ++n) {
                const int c = wc * 32 + n * 16 + (lane & 15);
                const int off = c * 64 + ((kg ^ (c & 7)) << 3);
                bfh[n] = *(const s16x8*)&Bh[off];
                bfl[n] = *(const s16x8*)&Bl[off];
            }
            #pragma unroll
            for (int m = 0; m < 2; ++m)
                #pragma unroll
                for (int n = 0; n < 2; ++n) {
                    acc[m][n] = MFMA(afh[m], bfh[n], acc[m][n], 0, 0, 0);
                    acc[m][n] = MFMA(afh[m], bfl[n], acc[m][n], 0, 0, 0);
                    acc[m][n] = MFMA(afl[m], bfh[n], acc[m][n], 0, 0, 0);
                }
        }
        SCHED0(); SBAR(); SCHED0();
    }

    // ---- e: row sums of squares (64 cols of this head)
    #pragma unroll
    for (int m = 0; m < 2; ++m)
        #pragma unroll
        for (int j = 0; j < 4; ++j) {
            float p = acc[m][0][j] * acc[m][0][j] + acc[m][1][j] * acc[m][1][j];
            p += __shfl_xor(p, 1, 64);
            p += __shfl_xor(p, 2, 64);
            p += __shfl_xor(p, 4, 64);
            p += __shfl_xor(p, 8, 64);
            if ((lane & 15) == 0)
                red[wr * 32 + m * 16 + (lane >> 4) * 4 + j][wc] = p;
        }

    // ---- WhT transpose via LDS (reuse Ah/Al)
    __syncthreads();
    ushort_t* Th = Ah;
    ushort_t* Tl = Al;
    #pragma unroll
    for (int m = 0; m < 2; ++m)
        #pragma unroll
        for (int n = 0; n < 2; ++n)
            #pragma unroll
            for (int j = 0; j < 4; ++j) {
                const int rr = wr * 32 + m * 16 + (lane >> 4) * 4 + j;
                const int cc = wc * 32 + n * 16 + (lane & 15);
                const int ad = cc * 64 + ((((rr >> 3) ^ (cc & 7))) << 3) + (rr & 7);
                ushort_t hh, ll;
                split2(acc[m][n][j], hh, ll);
                Th[ad] = hh; Tl[ad] = ll;
            }
    __syncthreads();

    if (tid < 64) {
        const int rg = row0 + tid;
        e_out[((size_t)((rg >> 11) * NH + head)) * NNODE + (rg & 2047)] =
            red[tid][0] + red[tid][1];
    }
    const int bb = row0 >> 11, node0 = row0 & 2047;
    #pragma unroll
    for (int i = 0; i < 2; ++i) {
        const int gid = tid + 256 * i;
        const int c = gid >> 3, gr = gid & 7;
        const int ad = c * 64 + ((gr ^ (c & 7)) << 3);
        uint4 vh = *(const uint4*)&Th[ad];
        uint4 vl = *(const uint4*)&Tl[ad];
        const size_t o = ((size_t)bb * HD + col0 + c) * NNODE + node0 + gr * 8;
        *(uint4*)&WhT_hi[o] = vh;
        *(uint4*)&WhT_lo[o] = vl;
    }
}

// ---------------------------------------------------------------------------
// softmax stats + att
// ---------------------------------------------------------------------------
__global__ __launch_bounds__(256) void sm_kernel(
    const float* __restrict__ e, float* __restrict__ ms)
{
    __shared__ float red[8];
    const int bh = blockIdx.x, tid = threadIdx.x;
    const int lane = tid & 63, w = tid >> 6;
    const float* row = e + (size_t)bh * NNODE;
    float mx = -3.0e38f;
    for (int n = tid; n < NNODE; n += 256) mx = fmaxf(mx, row[n]);
    #pragma unroll
    for (int off = 32; off; off >>= 1) mx = fmaxf(mx, __shfl_xor(mx, off, 64));
    if (lane == 0) red[w] = mx;
    __syncthreads();
    mx = fmaxf(fmaxf(red[0], red[1]), fmaxf(red[2], red[3]));
    float s = 0.f;
    for (int n = tid; n < NNODE; n += 256) s += expf(row[n] - mx);
    #pragma unroll
    for (int off = 32; off; off >>= 1) s += __shfl_xor(s, off, 64);
    if (lane == 0) red[4 + w] = s;
    __syncthreads();
    if (tid == 0) {
        ms[bh * 2] = mx;
        ms[bh * 2 + 1] = red[4] + red[5] + red[6] + red[7];
    }
}

__global__ __launch_bounds__(256) void att_kernel(
    const float* __restrict__ e, const float* __restrict__ ms,
    float* __restrict__ attv)
{
    const int i = blockIdx.x * 256 + threadIdx.x;
    const int b = i >> 11, n = i & 2047;
    float a = 0.f;
    #pragma unroll
    for (int h = 0; h < NH; ++h) {
        const int bh = b * NH + h;
        a += expf(e[(size_t)bh * NNODE + n] - ms[bh * 2]) / ms[bh * 2 + 1];
    }
    attv[i] = 0.25f * a;
}

// ---------------------------------------------------------------------------
// GEMM2: out = relu(att[row]*(adj @ Wh) + bias). 128x64 tiles, BK=64.
// 1D grid 512, XCD-swizzled so each XCD owns one batch (B panels L2-resident).
// R6 structure: A fp32 global->reg, single RNE bf16 convert (adj-rounding
// error ~0.1 absmax, under threshold); B hi/lo tri-buffered LDS via
// global_load_lds; ONE barrier + counted vmcnt per K-tile; MFMA emitted in
// 2 independence passes (dep distance 8).
// ---------------------------------------------------------------------------
__global__ __launch_bounds__(256, 2) void gemm2_kernel(
    const float* __restrict__ adj,
    const ushort_t* __restrict__ WhT_hi,
    const ushort_t* __restrict__ WhT_lo,
    const float* __restrict__ att,
    const float* __restrict__ bias,
    float* __restrict__ out)
{
    __shared__ __align__(16) ushort_t Bh[3][64 * 64];   // 3 x 8 KB
    __shared__ __align__(16) ushort_t Bl[3][64 * 64];   // 3 x 8 KB

    const int tid = threadIdx.x, lane = tid & 63, w = tid >> 6;

    // XCD-chunked swizzle (512 = 8 XCD x 64): XCD n gets wg [n*64, n*64+64)
    // = all 64 tiles of batch n  ->  batch's 2 MB WhT panels stay in its L2.
    const int bid = blockIdx.x;
    const int wg = (bid & 7) * 64 + (bid >> 3);
    const int bx = wg & 15, by = (wg >> 4) & 3, b = wg >> 6;
    const int row0 = bx * 128, col0 = by * 64;

    const ushort_t* Bhg = WhT_hi + ((size_t)b * HD + col0) * NNODE;
    const ushort_t* Blg = WhT_lo + ((size_t)b * HD + col0) * NNODE;

    // A: row = row0 + w*32 + (lane&15) (+16 for m=1); k = (lane>>4)*8
    const float* pA = adj + (size_t)b * NNODE * NNODE
                    + (size_t)(row0 + w * 32 + (lane & 15)) * NNODE
                    + ((lane >> 4) * 8);

    const int bc = lane >> 3, bs = lane & 7;

    f32x4 ar[2][2][2];          // [m][ks][half] raw A(t) / A(t+1) in flight
    s16x8 afh[2][2];            // converted A frags [m][ks] (single bf16)
    f32x4 acc[2][4];
    #pragma unroll
    for (int m = 0; m < 2; ++m)
        #pragma unroll
        for (int n = 0; n < 4; ++n) acc[m][n] = (f32x4)0.f;

    #define G2_LOADA(K0) do {                                                   \
        _Pragma("unroll")                                                       \
        for (int m = 0; m < 2; ++m)                                             \
        _Pragma("unroll")                                                       \
        for (int ks = 0; ks < 2; ++ks) {                                        \
            ar[m][ks][0] = *(const f32x4*)&pA[(size_t)m * 16 * NNODE + (K0) + ks * 32]; \
            ar[m][ks][1] = *(const f32x4*)&pA[(size_t)m * 16 * NNODE + (K0) + ks * 32 + 4]; \
        }                                                                       \
    } while (0)

    #define G2_CONVERT() do {                                                   \
        _Pragma("unroll")                                                       \
        for (int m = 0; m < 2; ++m)                                             \
        _Pragma("unroll")                                                       \
        for (int ks = 0; ks < 2; ++ks)                                          \
        _Pragma("unroll")                                                       \
        for (int h2 = 0; h2 < 2; ++h2)                                          \
        _Pragma("unroll")                                                       \
        for (int j = 0; j < 4; ++j)                                             \
            afh[m][ks][h2 * 4 + j] = (short)f2bf(ar[m][ks][h2][j]);             \
    } while (0)

    #define G2_STAGEB(BUF, K0) do {                                             \
        _Pragma("unroll")                                                       \
        for (int qq = 0; qq < 2; ++qq) {                                        \
            const int q = w + qq * 4;                                           \
            const int c = q * 8 + bc;                                           \
            const int g = bs ^ (c & 7);                                         \
            GLOAD16(&Bhg[(size_t)c * NNODE + (K0) + g * 8], &Bh[BUF][q * 512]); \
            GLOAD16(&Blg[(size_t)c * NNODE + (K0) + g * 8], &Bl[BUF][q * 512]); \
        }                                                                       \
    } while (0)

    #define G2_COMPUTE(BHP, BLP) do {                                           \
        _Pragma("unroll")                                                       \
        for (int ks = 0; ks < 2; ++ks) {                                        \
            const int kg = ks * 4 + (lane >> 4);                                \
            s16x8 bfh[4], bfl[4];                                               \
            _Pragma("unroll")                                                   \
            for (int n = 0; n < 4; ++n) {                                       \
                const int c = n * 16 + (lane & 15);                             \
                const int off = c * 64 + ((kg ^ (c & 7)) << 3);                 \
                bfh[n] = *(const s16x8*)&(BHP)[off];                            \
                bfl[n] = *(const s16x8*)&(BLP)[off];                            \
            }                                                                   \
            __builtin_amdgcn_s_setprio(1);                                      \
            _Pragma("unroll")                                                   \
            for (int m = 0; m < 2; ++m)                                         \
            _Pragma("unroll")                                                   \
            for (int n = 0; n < 4; ++n)                                         \
                acc[m][n] = MFMA(afh[m][ks], bfh[n], acc[m][n], 0, 0, 0);       \
            _Pragma("unroll")                                                   \
            for (int m = 0; m < 2; ++m)                                         \
            _Pragma("unroll")                                                   \
            for (int n = 0; n < 4; ++n)                                         \
                acc[m][n] = MFMA(afh[m][ks], bfl[n], acc[m][n], 0, 0, 0);       \
            __builtin_amdgcn_s_setprio(0);                                      \
        }                                                                       \
    } while (0)

    // prologue: B(0) issued FIRST (older than A(0) -> any A-wait drains it)
    G2_STAGEB(0, 0);
    G2_LOADA(0);

    int cur = 0;
    for (int t = 0; t < 32; ++t) {
        const int nxt = (cur == 2) ? 0 : cur + 1;
        if (t < 31) G2_STAGEB(nxt, (t + 1) * 64);
        G2_CONVERT();                      // consumes A(t); implicit wait drains B(t) too
        if (t < 31) G2_LOADA((t + 1) * 64);
        // outstanding newest = B(t+1):4 + A(t+1):8 = 12 -> vmcnt(12) drains B(t)
        asm volatile("s_waitcnt vmcnt(12)" ::: "memory");
        SCHED0(); SBAR(); SCHED0();
        {
            const ushort_t* bhp = &Bh[cur][0];
            const ushort_t* blp = &Bl[cur][0];
            G2_COMPUTE(bhp, blp);
        }
        cur = nxt;
        // no trailing barrier: triple-buffer + <=1-iter wave skew keeps
        // writer buf (t+2)%3 disjoint from reader bufs t%3 and (t+1)%3.
    }

    // epilogue
    const float* attb = att + (size_t)b * NNODE;
    #pragma unroll
    for (int n = 0; n < 4; ++n) {
        const int c = col0 + n * 16 + (lane & 15);
        const float bv = bias[c];
        #pragma unroll
        for (int m = 0; m < 2; ++m)
            #pragma unroll
            for (int j = 0; j < 4; ++j) {
                const int row = row0 + w * 32 + m * 16 + (lane >> 4) * 4 + j;
                out[((size_t)b * NNODE + row) * HD + c] =
                    fmaxf(fmaf(acc[m][n][j], attb[row], bv), 0.f);
            }
    }
}

extern "C" void kernel_launch(void* const* d_in, const int* in_sizes, int n_in,
                              void* d_out, int out_size, void* d_ws, size_t ws_size,
                              hipStream_t stream) {
    const float* features = (const float*)d_in[0];
    const float* adj      = (const float*)d_in[1];
    const float* Wm       = (const float*)d_in[2];
    const float* bias     = (const float*)d_in[3];
    float* out = (float*)d_out;

    ushort_t* WhT_hi = (ushort_t*)d_ws;
    ushort_t* WhT_lo = WhT_hi + (size_t)BATCH * HD * NNODE;
    ushort_t* wt_hi  = WhT_lo + (size_t)BATCH * HD * NNODE;
    ushort_t* wt_lo  = wt_hi + FDIM * HD;
    float* e    = (float*)(wt_lo + FDIM * HD);
    float* ms   = e + (size_t)BATCH * NH * NNODE;
    float* attv = ms + 64;

    wprep_kernel<<<HD, 256, 0, stream>>>(Wm, wt_hi, wt_lo);
    gemm1_kernel<<<dim3(MROWS / 64, NH), 256, 0, stream>>>(
        features, wt_hi, wt_lo, WhT_hi, WhT_lo, e);
    sm_kernel<<<BATCH * NH, 256, 0, stream>>>(e, ms);
    att_kernel<<<MROWS / 256, 256, 0, stream>>>(e, ms, attv);
    gemm2_kernel<<<512, 256, 0, stream>>>(
        adj, WhT_hi, WhT_lo, attv, bias, out);
}

// Round 9
// 265.362 us; speedup vs baseline: 1.3309x; 1.0087x over previous
//
#include <hip/hip_runtime.h>
#include <hip/hip_bf16.h>

#define BATCH 8
#define NNODE 2048
#define FDIM 256
#define HD 256
#define NH 4
#define MROWS (BATCH*NNODE)

typedef float f32x4 __attribute__((ext_vector_type(4)));
typedef short s16x8 __attribute__((ext_vector_type(8)));
typedef unsigned short ushort_t;

#define MFMA __builtin_amdgcn_mfma_f32_16x16x32_bf16
#define SCHED0() __builtin_amdgcn_sched_barrier(0)
#define SBAR() __builtin_amdgcn_s_barrier()

// RNE round to bf16
__device__ __forceinline__ ushort_t f2bf(float f) {
    unsigned u = __builtin_bit_cast(unsigned, f);
    u += 0x7fffu + ((u >> 16) & 1u);
    return (ushort_t)(u >> 16);
}
// truncation hi/lo split: f = hi + lo + eps, |eps| <= 2^-16 |f|
__device__ __forceinline__ void split2(float f, ushort_t& h, ushort_t& l) {
    unsigned u = __builtin_bit_cast(unsigned, f);
    h = (ushort_t)(u >> 16);
    float fh = __builtin_bit_cast(float, u & 0xffff0000u);
    float lo = f - fh;                       // exact
    l = (ushort_t)(__builtin_bit_cast(unsigned, lo) >> 16);
}

// global -> LDS direct (wave-uniform LDS base + lane*16; per-lane global src)
#define GLOAD16(gp, lp) __builtin_amdgcn_global_load_lds( \
    (const __attribute__((address_space(1))) void*)(gp),  \
    (__attribute__((address_space(3))) void*)(lp), 16, 0, 0)

// ---------------------------------------------------------------------------
// wprep: wt_hi/lo[n][k] = trunc-split(W[k][n])  (gemm1's B stays split: e needs it)
// ---------------------------------------------------------------------------
__global__ __launch_bounds__(256) void wprep_kernel(
    const float* __restrict__ Wm,
    ushort_t* __restrict__ wt_hi, ushort_t* __restrict__ wt_lo)
{
    const int nn = blockIdx.x, k = threadIdx.x;
    ushort_t h, l;
    split2(Wm[(size_t)k * HD + nn], h, l);
    wt_hi[nn * FDIM + k] = h;
    wt_lo[nn * FDIM + k] = l;
}

// ---------------------------------------------------------------------------
// GEMM1: Wh = features @ W. 64x64 tiles, BK=64, K=256 (4 tiles).
// grid (256, 4); 4 waves 2x2; wave tile 32x32. Emits WhT_hi (RNE) + e (fp32).
// ---------------------------------------------------------------------------
__global__ __launch_bounds__(256, 4) void gemm1_kernel(
    const float* __restrict__ features,
    const ushort_t* __restrict__ wt_hi,
    const ushort_t* __restrict__ wt_lo,
    ushort_t* __restrict__ WhT_hi,
    float* __restrict__ e_out)
{
    __shared__ __align__(16) ushort_t Ah[64 * 64];
    __shared__ __align__(16) ushort_t Al[64 * 64];
    __shared__ __align__(16) ushort_t Bh[64 * 64];
    __shared__ __align__(16) ushort_t Bl[64 * 64];
    __shared__ float red[64][2];

    const int tid = threadIdx.x, lane = tid & 63, w = tid >> 6;
    const int wr = w >> 1, wc = w & 1;
    const int row0 = blockIdx.x * 64;
    const int head = blockIdx.y;
    const int col0 = head * 64;

    const float* Ab = features + (size_t)row0 * FDIM;
    const ushort_t* Bhg = wt_hi + (size_t)col0 * FDIM;
    const ushort_t* Blg = wt_lo + (size_t)col0 * FDIM;

    const int sr0 = tid >> 3;
    const int sg8 = tid & 7;
    const int bc = (lane >> 3);
    const int bs = lane & 7;

    f32x4 ar[4];
    f32x4 acc[2][2];
    #pragma unroll
    for (int m = 0; m < 2; ++m)
        #pragma unroll
        for (int n = 0; n < 2; ++n) acc[m][n] = (f32x4)0.f;

    #define G1_LOADA(K0) do {                                                  \
        _Pragma("unroll")                                                      \
        for (int i = 0; i < 2; ++i) {                                          \
            const int r = sr0 + 32 * i;                                        \
            ar[2*i]   = *(const f32x4*)&Ab[(size_t)r * FDIM + (K0) + sg8 * 8]; \
            ar[2*i+1] = *(const f32x4*)&Ab[(size_t)r * FDIM + (K0) + sg8 * 8 + 4]; \
        }                                                                      \
    } while (0)

    #define G1_STAGEA() do {                                                   \
        _Pragma("unroll")                                                      \
        for (int i = 0; i < 2; ++i) {                                          \
            const int r = sr0 + 32 * i;                                        \
            s16x8 vh, vl; ushort_t hh, ll;                                     \
            _Pragma("unroll")                                                  \
            for (int j = 0; j < 4; ++j) {                                      \
                split2(ar[2*i][j], hh, ll);  vh[j] = (short)hh; vl[j] = (short)ll; \
            }                                                                  \
            _Pragma("unroll")                                                  \
            for (int j = 0; j < 4; ++j) {                                      \
                split2(ar[2*i+1][j], hh, ll); vh[4+j] = (short)hh; vl[4+j] = (short)ll; \
            }                                                                  \
            const int off = r * 64 + ((sg8 ^ (r & 7)) << 3);                   \
            *(s16x8*)&Ah[off] = vh; *(s16x8*)&Al[off] = vl;                    \
        }                                                                      \
    } while (0)

    #define G1_STAGEB(K0) do {                                                 \
        _Pragma("unroll")                                                      \
        for (int qq = 0; qq < 2; ++qq) {                                       \
            const int q = w + qq * 4;                                          \
            const int c = q * 8 + bc;                                          \
            const int g = bs ^ (c & 7);                                        \
            GLOAD16(&Bhg[(size_t)c * FDIM + (K0) + g * 8], &Bh[q * 512]);      \
            GLOAD16(&Blg[(size_t)c * FDIM + (K0) + g * 8], &Bl[q * 512]);      \
        }                                                                      \
    } while (0)

    G1_LOADA(0);
    for (int t = 0; t < 4; ++t) {
        G1_STAGEB(t * 64);
        G1_STAGEA();
        if (t < 3) G1_LOADA((t + 1) * 64);
        if (t < 3) { asm volatile("s_waitcnt lgkmcnt(0) vmcnt(4)" ::: "memory"); }
        else       { asm volatile("s_waitcnt lgkmcnt(0) vmcnt(0)" ::: "memory"); }
        SCHED0(); SBAR(); SCHED0();
        #pragma unroll
        for (int kh = 0; kh < 2; ++kh) {
            const int kg = kh * 4 + (lane >> 4);
            s16x8 afh[2], afl[2], bfh[2], bfl[2];
            #pragma unroll
            for (int m = 0; m < 2; ++m) {
                const int r = wr * 32 + m * 16 + (lane & 15);
                const int off = r * 64 + ((kg ^ (r & 7)) << 3);
                afh[m] = *(const s16x8*)&Ah[off];
                afl[m] = *(const s16x8*)&Al[off];
            }
            #pragma unroll
            for (int n = 0; n < 2; ++n) {
                const int c = wc * 32 + n * 16 + (lane & 15);
                const int off = c * 64 + ((kg ^ (c & 7)) << 3);
                bfh[n] = *(const s16x8*)&Bh[off];
                bfl[n] = *(const s16x8*)&Bl[off];
            }
            #pragma unroll
            for (int m = 0; m < 2; ++m)
                #pragma unroll
                for (int n = 0; n < 2; ++n) {
                    acc[m][n] = MFMA(afh[m], bfh[n], acc[m][n], 0, 0, 0);
                    acc[m][n] = MFMA(afh[m], bfl[n], acc[m][n], 0, 0, 0);
                    acc[m][n] = MFMA(afl[m], bfh[n], acc[m][n], 0, 0, 0);
                }
        }
        SCHED0(); SBAR(); SCHED0();
    }

    // ---- e: row sums of squares (64 cols of this head), fp32
    #pragma unroll
    for (int m = 0; m < 2; ++m)
        #pragma unroll
        for (int j = 0; j < 4; ++j) {
            float p = acc[m][0][j] * acc[m][0][j] + acc[m][1][j] * acc[m][1][j];
            p += __shfl_xor(p, 1, 64);
            p += __shfl_xor(p, 2, 64);
            p += __shfl_xor(p, 4, 64);
            p += __shfl_xor(p, 8, 64);
            if ((lane & 15) == 0)
                red[wr * 32 + m * 16 + (lane >> 4) * 4 + j][wc] = p;
        }

    // ---- WhT (RNE bf16, hi only) via LDS transpose
    __syncthreads();
    ushort_t* Th = Ah;
    #pragma unroll
    for (int m = 0; m < 2; ++m)
        #pragma unroll
        for (int n = 0; n < 2; ++n)
            #pragma unroll
            for (int j = 0; j < 4; ++j) {
                const int rr = wr * 32 + m * 16 + (lane >> 4) * 4 + j;
                const int cc = wc * 32 + n * 16 + (lane & 15);
                const int ad = cc * 64 + ((((rr >> 3) ^ (cc & 7))) << 3) + (rr & 7);
                Th[ad] = f2bf(acc[m][n][j]);
            }
    __syncthreads();

    if (tid < 64) {
        const int rg = row0 + tid;
        e_out[((size_t)((rg >> 11) * NH + head)) * NNODE + (rg & 2047)] =
            red[tid][0] + red[tid][1];
    }
    const int bb = row0 >> 11, node0 = row0 & 2047;
    {
        const int gid = tid + 256 * 0;       // 512 granules over 2 iters
        #pragma unroll
        for (int i = 0; i < 2; ++i) {
            const int g2 = gid + 256 * i;
            const int c = g2 >> 3, gr = g2 & 7;
            const int ad = c * 64 + ((gr ^ (c & 7)) << 3);
            uint4 vh = *(const uint4*)&Th[ad];
            const size_t o = ((size_t)bb * HD + col0 + c) * NNODE + node0 + gr * 8;
            *(uint4*)&WhT_hi[o] = vh;
        }
    }
}

// ---------------------------------------------------------------------------
// softmax stats: ms[bh*2] = max, ms[bh*2+1] = 1/sum
// ---------------------------------------------------------------------------
__global__ __launch_bounds__(256) void sm_kernel(
    const float* __restrict__ e, float* __restrict__ ms)
{
    __shared__ float red[8];
    const int bh = blockIdx.x, tid = threadIdx.x;
    const int lane = tid & 63, w = tid >> 6;
    const float* row = e + (size_t)bh * NNODE;
    float mx = -3.0e38f;
    for (int n = tid; n < NNODE; n += 256) mx = fmaxf(mx, row[n]);
    #pragma unroll
    for (int off = 32; off; off >>= 1) mx = fmaxf(mx, __shfl_xor(mx, off, 64));
    if (lane == 0) red[w] = mx;
    __syncthreads();
    mx = fmaxf(fmaxf(red[0], red[1]), fmaxf(red[2], red[3]));
    float s = 0.f;
    for (int n = tid; n < NNODE; n += 256) s += expf(row[n] - mx);
    #pragma unroll
    for (int off = 32; off; off >>= 1) s += __shfl_xor(s, off, 64);
    if (lane == 0) red[4 + w] = s;
    __syncthreads();
    if (tid == 0) {
        ms[bh * 2] = mx;
        ms[bh * 2 + 1] = 1.0f / (red[4] + red[5] + red[6] + red[7]);
    }
}

// ---------------------------------------------------------------------------
// GEMM2: out = relu(att[row]*(adj @ Wh) + bias), att computed in epilogue.
// 128x64 tiles, BK=64, grid 512 XCD-swizzled. A fp32 global->reg (2-deep,
// even/odd named sets), single RNE bf16. B single RNE bf16 via gload_lds,
// 4-buffer LDS rotation, staged 2 tiles ahead (B before A per tile => A-wait
// implies B drained). One barrier per tile. 16 MFMA/wave/tile.
// ---------------------------------------------------------------------------
__global__ __launch_bounds__(256, 2) void gemm2_kernel(
    const float* __restrict__ adj,
    const ushort_t* __restrict__ WhT_hi,
    const float* __restrict__ e,
    const float* __restrict__ ms,
    const float* __restrict__ bias,
    float* __restrict__ out)
{
    __shared__ __align__(16) ushort_t Bh[4][64 * 64];   // 4 x 8 KB

    const int tid = threadIdx.x, lane = tid & 63, w = tid >> 6;

    // XCD-chunked swizzle (512 = 8 XCD x 64): XCD n owns batch n entirely.
    const int bid = blockIdx.x;
    const int wg = (bid & 7) * 64 + (bid >> 3);
    const int bx = wg & 15, by = (wg >> 4) & 3, b = wg >> 6;
    const int row0 = bx * 128, col0 = by * 64;

    const ushort_t* Bhg = WhT_hi + ((size_t)b * HD + col0) * NNODE;
    const float* pA = adj + (size_t)b * NNODE * NNODE
                    + (size_t)(row0 + w * 32 + (lane & 15)) * NNODE
                    + ((lane >> 4) * 8);

    const int bc = lane >> 3, bs = lane & 7;

    f32x4 arE[8], arO[8];       // [m*4 + ks*2 + half], even/odd tile sets
    s16x8 afh[2][2];            // converted A frags [m][ks]
    f32x4 acc[2][4];
    #pragma unroll
    for (int m = 0; m < 2; ++m)
        #pragma unroll
        for (int n = 0; n < 4; ++n) acc[m][n] = (f32x4)0.f;

    #define G2_LOADA(AR, K0) do {                                               \
        _Pragma("unroll")                                                       \
        for (int m = 0; m < 2; ++m)                                             \
        _Pragma("unroll")                                                       \
        for (int ks = 0; ks < 2; ++ks) {                                        \
            AR[m*4+ks*2+0] = *(const f32x4*)&pA[(size_t)m * 16 * NNODE + (K0) + ks * 32]; \
            AR[m*4+ks*2+1] = *(const f32x4*)&pA[(size_t)m * 16 * NNODE + (K0) + ks * 32 + 4]; \
        }                                                                       \
    } while (0)

    #define G2_CONVERT(AR) do {                                                 \
        _Pragma("unroll")                                                       \
        for (int m = 0; m < 2; ++m)                                             \
        _Pragma("unroll")                                                       \
        for (int ks = 0; ks < 2; ++ks)                                          \
        _Pragma("unroll")                                                       \
        for (int h2 = 0; h2 < 2; ++h2)                                          \
        _Pragma("unroll")                                                       \
        for (int j = 0; j < 4; ++j)                                             \
            afh[m][ks][h2 * 4 + j] = (short)f2bf(AR[m*4+ks*2+h2][j]);           \
    } while (0)

    #define G2_STAGEB(BUF, K0) do {                                             \
        _Pragma("unroll")                                                       \
        for (int qq = 0; qq < 2; ++qq) {                                        \
            const int q = w + qq * 4;                                           \
            const int c = q * 8 + bc;                                           \
            const int g = bs ^ (c & 7);                                         \
            GLOAD16(&Bhg[(size_t)c * NNODE + (K0) + g * 8], &Bh[BUF][q * 512]); \
        }                                                                       \
    } while (0)

    #define G2_COMPUTE(BUF) do {                                                \
        _Pragma("unroll")                                                       \
        for (int ks = 0; ks < 2; ++ks) {                                        \
            const int kg = ks * 4 + (lane >> 4);                                \
            s16x8 bfh[4];                                                       \
            _Pragma("unroll")                                                   \
            for (int n = 0; n < 4; ++n) {                                       \
                const int c = n * 16 + (lane & 15);                             \
                const int off = c * 64 + ((kg ^ (c & 7)) << 3);                 \
                bfh[n] = *(const s16x8*)&Bh[BUF][off];                          \
            }                                                                   \
            __builtin_amdgcn_s_setprio(1);                                      \
            _Pragma("unroll")                                                   \
            for (int m = 0; m < 2; ++m)                                         \
            _Pragma("unroll")                                                   \
            for (int n = 0; n < 4; ++n)                                         \
                acc[m][n] = MFMA(afh[m][ks], bfh[n], acc[m][n], 0, 0, 0);       \
            __builtin_amdgcn_s_setprio(0);                                      \
        }                                                                       \
    } while (0)

    // TILE: stage buf for tile+2 (B FIRST, then A refill of same set),
    // convert current A, one barrier, compute. Convert's implicit wait on
    // A(t) also drains B(t) (B issued before A at tile t-2).
    #define G2_TILE(AR, CBUF, SBUF, KC, DO_STAGE) do {                          \
        if (DO_STAGE) G2_STAGEB(SBUF, (KC) + 128);                              \
        G2_CONVERT(AR);                                                         \
        if (DO_STAGE) G2_LOADA(AR, (KC) + 128);                                 \
        asm volatile("s_waitcnt vmcnt(20)" ::: "memory");                       \
        SCHED0(); SBAR(); SCHED0();                                             \
        G2_COMPUTE(CBUF);                                                       \
    } while (0)

    // prologue: tiles 0,1 staged (B before A per tile)
    G2_STAGEB(0, 0);
    G2_LOADA(arE, 0);
    G2_STAGEB(1, 64);
    G2_LOADA(arO, 64);

    #pragma unroll 1
    for (int t = 0; t < 28; t += 4) {
        G2_TILE(arE, 0, 2, t * 64, true);
        G2_TILE(arO, 1, 3, (t + 1) * 64, true);
        G2_TILE(arE, 2, 0, (t + 2) * 64, true);
        G2_TILE(arO, 3, 1, (t + 3) * 64, true);
    }
    G2_TILE(arE, 0, 2, 28 * 64, true);    // stages tile 30
    G2_TILE(arO, 1, 3, 29 * 64, true);    // stages tile 31
    G2_TILE(arE, 2, 0, 30 * 64, false);
    G2_TILE(arO, 3, 0, 31 * 64, false);

    // ---- epilogue: att inline + bias + relu
    float msm[NH], msi[NH];
    #pragma unroll
    for (int h = 0; h < NH; ++h) {
        msm[h] = ms[(b * NH + h) * 2];
        msi[h] = ms[(b * NH + h) * 2 + 1];
    }
    float rowatt[2][4];
    #pragma unroll
    for (int m = 0; m < 2; ++m)
        #pragma unroll
        for (int j = 0; j < 4; ++j) {
            const int row = row0 + w * 32 + m * 16 + (lane >> 4) * 4 + j;
            float a = 0.f;
            #pragma unroll
            for (int h = 0; h < NH; ++h)
                a += expf(e[((size_t)b * NH + h) * NNODE + row] - msm[h]) * msi[h];
            rowatt[m][j] = 0.25f * a;
        }
    #pragma unroll
    for (int n = 0; n < 4; ++n) {
        const int c = col0 + n * 16 + (lane & 15);
        const float bv = bias[c];
        #pragma unroll
        for (int m = 0; m < 2; ++m)
            #pragma unroll
            for (int j = 0; j < 4; ++j) {
                const int row = row0 + w * 32 + m * 16 + (lane >> 4) * 4 + j;
                out[((size_t)b * NNODE + row) * HD + c] =
                    fmaxf(fmaf(acc[m][n][j], rowatt[m][j], bv), 0.f);
            }
    }
}

extern "C" void kernel_launch(void* const* d_in, const int* in_sizes, int n_in,
                              void* d_out, int out_size, void* d_ws, size_t ws_size,
                              hipStream_t stream) {
    const float* features = (const float*)d_in[0];
    const float* adj      = (const float*)d_in[1];
    const float* Wm       = (const float*)d_in[2];
    const float* bias     = (const float*)d_in[3];
    float* out = (float*)d_out;

    ushort_t* WhT_hi = (ushort_t*)d_ws;                          // 8.39 MB
    ushort_t* wt_hi  = WhT_hi + (size_t)BATCH * HD * NNODE;
    ushort_t* wt_lo  = wt_hi + FDIM * HD;
    float* e  = (float*)(wt_lo + FDIM * HD);
    float* ms = e + (size_t)BATCH * NH * NNODE;

    wprep_kernel<<<HD, 256, 0, stream>>>(Wm, wt_hi, wt_lo);
    gemm1_kernel<<<dim3(MROWS / 64, NH), 256, 0, stream>>>(
        features, wt_hi, wt_lo, WhT_hi, e);
    sm_kernel<<<BATCH * NH, 256, 0, stream>>>(e, ms);
    gemm2_kernel<<<512, 256, 0, stream>>>(
        adj, WhT_hi, e, ms, bias, out);
}